// Round 8
// baseline (171.112 us; speedup 1.0000x reference)
//
#include <hip/hip_runtime.h>

#define BSHIFT 7
#define BNODES 128
#define BMASK 127
#define CAP 6144
#define PT 256
#define EPB 4096            // edges per place block (16/thread)
#define TPB 256

// ---- bf16 pack/unpack helpers (RNE) ----
__device__ __forceinline__ unsigned pkbf2(float a, float b) {
    unsigned ua = __float_as_uint(a), ub = __float_as_uint(b);
    ua = (ua + 0x7fffu + ((ua >> 16) & 1u)) >> 16;
    ub = (ub + 0x7fffu + ((ub >> 16) & 1u)) >> 16;
    return ua | (ub << 16);
}
__device__ __forceinline__ float bflo(unsigned u) { return __uint_as_float(u << 16); }
__device__ __forceinline__ float bfhi(unsigned u) { return __uint_as_float(u & 0xffff0000u); }

// ---------------- fused: bucketed placement (write-combined, no binary search) + layer-1 GEMM ----------------
// blocks [0, pb): placement of 4096 edges each. blocks [pb, pb+gb): h = bf16(x @ W1) unscaled.
// smem (place): cnt@0(4096) bbs@4096(4096) cur@8192(4096) ssum@12288(256) stage@12544(16384) bko@28928(8192)
__global__ __launch_bounds__(PT) void fused_place_gemm_kernel(
    const void* __restrict__ ei,
    int* __restrict__ gcur, unsigned* __restrict__ pairs,
    const float* __restrict__ x, const float* __restrict__ W1,
    uint4* __restrict__ hs1u, int E, int nb, int pb, int N) {
    __shared__ alignas(16) char smem[37120];
    int tid = threadIdx.x;
    if ((int)blockIdx.x < pb) {
        int* cnt  = (int*)smem;                     // histogram -> per-bucket global base
        int* bbs  = (int*)(smem + 4096);            // local exclusive offsets
        int* cur  = (int*)(smem + 8192);            // scatter cursors
        int* ssum = (int*)(smem + 12288);           // wave totals + flag
        unsigned* stage = (unsigned*)(smem + 12544);
        unsigned short* bko = (unsigned short*)(smem + 28928);

        for (int i = tid; i < 1024; i += PT) cnt[i] = 0;
        if (tid == 0) ssum[8] = 0;
        // per-block int64 detection (first 1024 index pairs; L2-hit after first block)
        const unsigned* w = (const unsigned*)ei;
        int nz = 0;
        for (int k = tid; k < 1024; k += PT)
            if (w[2 * k + 1]) nz = 1;
        __syncthreads();
        if (nz) atomicOr(&ssum[8], 1);
        __syncthreads();
        const bool is64 = (ssum[8] == 0);
        const long long* e64 = (const long long*)ei;
        const int* e32 = (const int*)ei;
        int e0 = (int)blockIdx.x * EPB;
        int tot = E - e0; if (tot > EPB) tot = EPB;
        // pass 1: read edges once, histogram dst buckets, cache packed val + bucket in regs
        unsigned pk[16];
        int bk[16];
#pragma unroll
        for (int k = 0; k < 16; ++k) {
            int i = tid + k * PT;
            bk[k] = -1;
            if (i < tot) {
                int e = e0 + i;
                int s, d;
                if (is64) { s = (int)e64[e]; d = (int)e64[E + e]; }
                else      { s = e32[e];      d = e32[E + e]; }
                int b = d >> BSHIFT;
                bk[k] = b;
                pk[k] = ((unsigned)s << BSHIFT) | (unsigned)(d & BMASK);
                atomicAdd(&cnt[b], 1);
            }
        }
        __syncthreads();
        // wave-shfl scan over 1024 bins (4 bins/thread) + global reservation
        int b0 = tid * 4;
        int c0 = cnt[b0], c1 = cnt[b0 + 1], c2 = cnt[b0 + 2], c3 = cnt[b0 + 3];
        int t = c0 + c1 + c2 + c3;
        int v = t;
#pragma unroll
        for (int off = 1; off < 64; off <<= 1) {
            int u = __shfl_up(v, off);
            if ((tid & 63) >= off) v += u;
        }
        if ((tid & 63) == 63) ssum[tid >> 6] = v;
        __syncthreads();
        if (tid == 0) {
            int r = 0;
#pragma unroll
            for (int wv = 0; wv < 4; ++wv) { int xx = ssum[wv]; ssum[wv] = r; r += xx; }
        }
        __syncthreads();
        int excl = v - t + ssum[tid >> 6];
        int cs[4] = {c0, c1, c2, c3};
        int run = excl;
#pragma unroll
        for (int j = 0; j < 4; ++j) {
            int b = b0 + j;
            if (b < nb) {
                bbs[b] = run;
                int gb = cs[j] ? atomicAdd(&gcur[b], cs[j]) : 0;
                cnt[b] = gb;        // overwrite histogram with global base
                cur[b] = 0;
            }
            run += cs[j];
        }
        __syncthreads();
        // pass 2: pure-LDS scatter, record bucket id per staged slot
#pragma unroll
        for (int k = 0; k < 16; ++k) {
            if (bk[k] >= 0) {
                int b = bk[k];
                int r = atomicAdd(&cur[b], 1);
                int pos = bbs[b] + r;
                stage[pos] = pk[k];
                bko[pos] = (unsigned short)b;
            }
        }
        __syncthreads();
        // pass 3: coalesced global write (3 independent LDS reads, no search)
        for (int i = tid; i < tot; i += PT) {
            int b = bko[i];
            int slot = cnt[b] + (i - bbs[b]);
            if (slot < CAP) pairs[(size_t)b * CAP + slot] = stage[i];
        }
    } else {
        // ---- layer-1 GEMM: hs1u = bf16(x @ W1), unscaled ----
        float* Ws = (float*)smem;
        for (int i = tid; i < 2048; i += PT) Ws[i] = W1[i];
        __syncthreads();
        int n = ((int)blockIdx.x - pb) * PT + tid;
        if (n >= N) return;
        const float4* xp = (const float4*)(x + (size_t)n * 128);
        float a[16];
#pragma unroll
        for (int j = 0; j < 16; ++j) a[j] = 0.f;
#pragma unroll 4
        for (int k4 = 0; k4 < 32; ++k4) {
            float4 xv = xp[k4];
            const float* wr = &Ws[k4 * 64];
#pragma unroll
            for (int j = 0; j < 16; ++j) a[j] += xv.x * wr[j];
#pragma unroll
            for (int j = 0; j < 16; ++j) a[j] += xv.y * wr[16 + j];
#pragma unroll
            for (int j = 0; j < 16; ++j) a[j] += xv.z * wr[32 + j];
#pragma unroll
            for (int j = 0; j < 16; ++j) a[j] += xv.w * wr[48 + j];
        }
        uint4 u0, u1;
        u0.x = pkbf2(a[0], a[1]);   u0.y = pkbf2(a[2], a[3]);
        u0.z = pkbf2(a[4], a[5]);   u0.w = pkbf2(a[6], a[7]);
        u1.x = pkbf2(a[8], a[9]);   u1.y = pkbf2(a[10], a[11]);
        u1.z = pkbf2(a[12], a[13]); u1.w = pkbf2(a[14], a[15]);
        hs1u[(size_t)n * 2]     = u0;
        hs1u[(size_t)n * 2 + 1] = u1;
    }
}

// ---------------- counting sort -> fixed-slice CSR + deg + scaled bf16 pack of hs1 ----------------
__global__ __launch_bounds__(TPB) void csr_build_kernel(
    const unsigned* __restrict__ pairs, const int* __restrict__ gcur,
    int* __restrict__ csr, int* __restrict__ row, int* __restrict__ degA,
    const uint4* __restrict__ hs1u, uint4* __restrict__ hs1b, int N) {
    __shared__ int hist[BNODES];
    __shared__ int sc[BNODES];
    __shared__ int cur[BNODES];
    __shared__ int stage[CAP];
    int tid = threadIdx.x;
    int b = blockIdx.x;
    if (tid < BNODES) hist[tid] = 0;
    __syncthreads();
    int cnt = gcur[b]; if (cnt > CAP) cnt = CAP;
    int base = b * CAP;  // fixed slice: no global scan needed
    const unsigned* sl = pairs + (size_t)b * CAP;
    for (int i = tid; i < cnt; i += TPB)
        atomicAdd(&hist[sl[i] & BMASK], 1);
    __syncthreads();
    if (tid < BNODES) sc[tid] = hist[tid];
    __syncthreads();
    for (int off = 1; off < BNODES; off <<= 1) {
        int u = (tid < BNODES && tid >= off) ? sc[tid - off] : 0;
        __syncthreads();
        if (tid < BNODES) sc[tid] += u;
        __syncthreads();
    }
    if (tid < BNODES) {
        int excl = sc[tid] - hist[tid];
        sc[tid] = excl;
        cur[tid] = 0;
        int node = (b << BSHIFT) + tid;
        if (node < N) {
            row[node]  = base + excl;
            degA[node] = hist[tid];
        }
    }
    __syncthreads();
    for (int i = tid; i < cnt; i += TPB) {
        unsigned val = sl[i];
        int l = val & BMASK;
        int r = atomicAdd(&cur[l], 1);
        stage[sc[l] + r] = (int)(val >> BSHIFT);
    }
    __syncthreads();
    for (int i = tid; i < cnt; i += TPB)
        csr[base + i] = stage[i];
    // scale by dinv + repack: hs1b[node] = bf16(dinv * hs1u[node])
    {
        int ln = tid >> 1, half = tid & 1;
        int node = (b << BSHIFT) + ln;
        if (node < N) {
            float s = rsqrtf((float)(hist[ln] + 1));   // +1 self-loop
            uint4 uu = hs1u[(size_t)node * 2 + half];
            uint4 o;
            o.x = pkbf2(bflo(uu.x) * s, bfhi(uu.x) * s);
            o.y = pkbf2(bflo(uu.y) * s, bfhi(uu.y) * s);
            o.z = pkbf2(bflo(uu.z) * s, bfhi(uu.z) * s);
            o.w = pkbf2(bflo(uu.w) * s, bfhi(uu.w) * s);
            hs1b[(size_t)node * 2 + half] = o;
        }
    }
}

// ---------------- agg1: per-node bf16 register gather (4 lanes/node) + fused layer2 ----------------
__global__ __launch_bounds__(TPB) void agg1_kernel(
    const uint4* __restrict__ hs1b, const int* __restrict__ csr,
    const int* __restrict__ row, const int* __restrict__ degA,
    const float* __restrict__ W2, const float* __restrict__ b1,
    uint4* __restrict__ hs2b, int N) {
    __shared__ float Ws[112];
    __shared__ float bs[16];
    int tid = threadIdx.x;
    if (tid < 112) Ws[tid] = W2[tid];
    if (tid < 16) bs[tid] = b1[tid];
    __syncthreads();
    int g = blockIdx.x * TPB + tid;
    int n = g >> 2, quarter = g & 3;
    int st = 0, cnt = 0;
    if (n < N) { st = row[n]; cnt = degA[n]; }
    float acc[16];
#pragma unroll
    for (int j = 0; j < 16; ++j) acc[j] = 0.f;
    int i = st + quarter, end = st + cnt;
    for (; i + 4 < end; i += 8) {
        int s0 = csr[i], s1 = csr[i + 4];
        uint4 g0 = hs1b[(size_t)s0 * 2], g1 = hs1b[(size_t)s0 * 2 + 1];
        uint4 h0 = hs1b[(size_t)s1 * 2], h1 = hs1b[(size_t)s1 * 2 + 1];
        acc[0]  += bflo(g0.x) + bflo(h0.x); acc[1]  += bfhi(g0.x) + bfhi(h0.x);
        acc[2]  += bflo(g0.y) + bflo(h0.y); acc[3]  += bfhi(g0.y) + bfhi(h0.y);
        acc[4]  += bflo(g0.z) + bflo(h0.z); acc[5]  += bfhi(g0.z) + bfhi(h0.z);
        acc[6]  += bflo(g0.w) + bflo(h0.w); acc[7]  += bfhi(g0.w) + bfhi(h0.w);
        acc[8]  += bflo(g1.x) + bflo(h1.x); acc[9]  += bfhi(g1.x) + bfhi(h1.x);
        acc[10] += bflo(g1.y) + bflo(h1.y); acc[11] += bfhi(g1.y) + bfhi(h1.y);
        acc[12] += bflo(g1.z) + bflo(h1.z); acc[13] += bfhi(g1.z) + bfhi(h1.z);
        acc[14] += bflo(g1.w) + bflo(h1.w); acc[15] += bfhi(g1.w) + bfhi(h1.w);
    }
    if (i < end) {
        int s0 = csr[i];
        uint4 g0 = hs1b[(size_t)s0 * 2], g1 = hs1b[(size_t)s0 * 2 + 1];
        acc[0]  += bflo(g0.x); acc[1]  += bfhi(g0.x);
        acc[2]  += bflo(g0.y); acc[3]  += bfhi(g0.y);
        acc[4]  += bflo(g0.z); acc[5]  += bfhi(g0.z);
        acc[6]  += bflo(g0.w); acc[7]  += bfhi(g0.w);
        acc[8]  += bflo(g1.x); acc[9]  += bfhi(g1.x);
        acc[10] += bflo(g1.y); acc[11] += bfhi(g1.y);
        acc[12] += bflo(g1.z); acc[13] += bfhi(g1.z);
        acc[14] += bflo(g1.w); acc[15] += bfhi(g1.w);
    }
#pragma unroll
    for (int j = 0; j < 16; ++j) {
        acc[j] += __shfl_xor(acc[j], 1);
        acc[j] += __shfl_xor(acc[j], 2);
    }
    if (quarter == 0 && n < N) {
        float sc = rsqrtf((float)(cnt + 1));
        uint4 sA = hs1b[(size_t)n * 2], sB = hs1b[(size_t)n * 2 + 1];
        float self[16] = {bflo(sA.x), bfhi(sA.x), bflo(sA.y), bfhi(sA.y),
                          bflo(sA.z), bfhi(sA.z), bflo(sA.w), bfhi(sA.w),
                          bflo(sB.x), bfhi(sB.x), bflo(sB.y), bfhi(sB.y),
                          bflo(sB.z), bfhi(sB.z), bflo(sB.w), bfhi(sB.w)};
        float v[16];
#pragma unroll
        for (int j = 0; j < 16; ++j)
            v[j] = fmaxf(0.f, sc * (acc[j] + self[j]) + bs[j]);
        float h[7];
#pragma unroll
        for (int j = 0; j < 7; ++j) h[j] = 0.f;
#pragma unroll
        for (int k = 0; k < 16; ++k)
#pragma unroll
            for (int j = 0; j < 7; ++j) h[j] += v[k] * Ws[k * 7 + j];
        uint4 u;
        u.x = pkbf2(h[0] * sc, h[1] * sc);
        u.y = pkbf2(h[2] * sc, h[3] * sc);
        u.z = pkbf2(h[4] * sc, h[5] * sc);
        u.w = pkbf2(h[6] * sc, 0.f);
        hs2b[n] = u;
    }
}

// ---------------- agg2: per-node bf16 gather (8 lanes/node, 1 uint4/edge) + bias/log-softmax ----------------
__global__ __launch_bounds__(TPB) void agg2_kernel(
    const uint4* __restrict__ hs2b, const int* __restrict__ csr,
    const int* __restrict__ row, const int* __restrict__ degA,
    const float* __restrict__ b2, float* __restrict__ out, int N) {
    __shared__ float bs[8];
    if (threadIdx.x < 7) bs[threadIdx.x] = b2[threadIdx.x];
    __syncthreads();
    int g = blockIdx.x * TPB + threadIdx.x;
    int n = g >> 3, oct = g & 7;
    int st = 0, cnt = 0;
    if (n < N) { st = row[n]; cnt = degA[n]; }
    float acc[7];
#pragma unroll
    for (int j = 0; j < 7; ++j) acc[j] = 0.f;
    int i = st + oct, end = st + cnt;
    for (; i + 8 < end; i += 16) {
        int s0 = csr[i], s1 = csr[i + 8];
        uint4 q = hs2b[s0];
        uint4 r = hs2b[s1];
        acc[0] += bflo(q.x) + bflo(r.x); acc[1] += bfhi(q.x) + bfhi(r.x);
        acc[2] += bflo(q.y) + bflo(r.y); acc[3] += bfhi(q.y) + bfhi(r.y);
        acc[4] += bflo(q.z) + bflo(r.z); acc[5] += bfhi(q.z) + bfhi(r.z);
        acc[6] += bflo(q.w) + bflo(r.w);
    }
    if (i < end) {
        uint4 q = hs2b[csr[i]];
        acc[0] += bflo(q.x); acc[1] += bfhi(q.x);
        acc[2] += bflo(q.y); acc[3] += bfhi(q.y);
        acc[4] += bflo(q.z); acc[5] += bfhi(q.z);
        acc[6] += bflo(q.w);
    }
#pragma unroll
    for (int j = 0; j < 7; ++j) {
        acc[j] += __shfl_xor(acc[j], 1);
        acc[j] += __shfl_xor(acc[j], 2);
        acc[j] += __shfl_xor(acc[j], 4);
    }
    if (oct == 0 && n < N) {
        float sc = rsqrtf((float)(cnt + 1));
        uint4 q = hs2b[n];
        float self[7] = {bflo(q.x), bfhi(q.x), bflo(q.y), bfhi(q.y),
                         bflo(q.z), bfhi(q.z), bflo(q.w)};
        float v[7];
#pragma unroll
        for (int j = 0; j < 7; ++j)
            v[j] = sc * (acc[j] + self[j]) + bs[j];
        float m = v[0];
#pragma unroll
        for (int j = 1; j < 7; ++j) m = fmaxf(m, v[j]);
        float ssum = 0.f;
#pragma unroll
        for (int j = 0; j < 7; ++j) ssum += __expf(v[j] - m);
        float l = m + __logf(ssum);
        float* op = out + (size_t)n * 7;
#pragma unroll
        for (int j = 0; j < 7; ++j) op[j] = v[j] - l;
    }
}

extern "C" void kernel_launch(void* const* d_in, const int* in_sizes, int n_in,
                              void* d_out, int out_size, void* d_ws, size_t ws_size,
                              hipStream_t stream) {
    const float* x  = (const float*)d_in[0];
    const void*  ei = d_in[1];
    const float* W1 = (const float*)d_in[2];
    const float* b1 = (const float*)d_in[3];
    const float* W2 = (const float*)d_in[4];
    const float* b2 = (const float*)d_in[5];
    float* out = (float*)d_out;

    const int Hh  = in_sizes[3];            // 16
    const int Fin = in_sizes[2] / Hh;       // 128
    const int N   = in_sizes[0] / Fin;      // 100000
    const long long twoE = in_sizes[1];
    const int E = (int)(twoE / 2);          // 3200000
    const int nb = (N + BNODES - 1) >> BSHIFT;  // 782 buckets of 128 nodes
    (void)n_in; (void)out_size; (void)ws_size; (void)b1;

    char* p = (char*)d_ws;
    auto alloc = [&](size_t bytes) {
        char* r = p;
        p += (bytes + 63) & ~(size_t)63;
        return r;
    };
    int*      gcur  = (int*)alloc(sizeof(int) * (size_t)nb);
    unsigned* pairs = (unsigned*)alloc(sizeof(unsigned) * (size_t)nb * CAP);  // 19.2 MB
    int*      csr   = (int*)alloc(sizeof(int) * (size_t)nb * CAP);            // 19.2 MB (fixed slices)
    int*      rowA  = (int*)alloc(sizeof(int) * (size_t)N);
    int*      degA  = (int*)alloc(sizeof(int) * (size_t)N);
    uint4*    hs1u  = (uint4*)alloc(32 * (size_t)N);                          // 3.2 MB bf16 unscaled
    uint4*    hs1b  = (uint4*)alloc(32 * (size_t)N);                          // 3.2 MB bf16 scaled
    uint4*    hs2b  = (uint4*)alloc(16 * (size_t)N);                          // 1.6 MB bf16

    const int pb = (E + EPB - 1) / EPB;       // 782 place blocks
    const int gb = (N + PT - 1) / PT;         // 391 gemm blocks

    hipMemsetAsync(gcur, 0, sizeof(int) * (size_t)nb, stream);
    fused_place_gemm_kernel<<<pb + gb, PT, 0, stream>>>(
        ei, gcur, pairs, x, W1, hs1u, E, nb, pb, N);
    csr_build_kernel<<<nb, TPB, 0, stream>>>(pairs, gcur, csr, rowA, degA, hs1u, hs1b, N);
    agg1_kernel<<<(4 * N + TPB - 1) / TPB, TPB, 0, stream>>>(hs1b, csr, rowA, degA, W2,
                                                             (const float*)d_in[3], hs2b, N);
    agg2_kernel<<<(8 * N + TPB - 1) / TPB, TPB, 0, stream>>>(hs2b, csr, rowA, degA, b2, out, N);
}

// Round 9
// 113.091 us; speedup vs baseline: 1.5130x; 1.5130x over previous
//
#include <hip/hip_runtime.h>

#define BSHIFT 7
#define BNODES 128
#define BMASK 127
#define CAP 6144
#define PT 512               // fat-kernel threads
#define P_EPB (PT * 16)      // 8192 edges per place block
#define TPB 256

// ---- bf16 pack/unpack helpers (RNE) ----
__device__ __forceinline__ unsigned pkbf2(float a, float b) {
    unsigned ua = __float_as_uint(a), ub = __float_as_uint(b);
    ua = (ua + 0x7fffu + ((ua >> 16) & 1u)) >> 16;
    ub = (ub + 0x7fffu + ((ub >> 16) & 1u)) >> 16;
    return ua | (ub << 16);
}
__device__ __forceinline__ float bflo(unsigned u) { return __uint_as_float(u << 16); }
__device__ __forceinline__ float bfhi(unsigned u) { return __uint_as_float(u & 0xffff0000u); }

// ---------------- index dtype detection + gcur zero ----------------
__global__ void detect_kernel(const unsigned int* __restrict__ w, int* __restrict__ flag,
                              int* __restrict__ gcur, int nb) {
    __shared__ int any;
    if (threadIdx.x == 0) any = 0;
    __syncthreads();
    int nz = 0;
    for (int k = threadIdx.x; k < 1024; k += blockDim.x)
        if (w[2 * k + 1] != 0u) nz = 1;
    if (nz) atomicOr(&any, 1);
    for (int i = threadIdx.x; i < nb; i += blockDim.x) gcur[i] = 0;
    __syncthreads();
    if (threadIdx.x == 0) *flag = (any == 0) ? 1 : 0;  // 1 => int64
}

// ---------------- fused: bucketed placement (round-7 proven shape) + layer-1 GEMM (bf16 out) ----------------
// blocks [0, pb): placement. blocks [pb, pb+gb): hs1u = bf16(x @ W1) unscaled.
// smem layout (place path): cnt@0(4096) bbs@4096(4112) cur@8208(4096) ssum@12304(2048) stage@14352(32768)
__global__ __launch_bounds__(PT) void fused_place_gemm_kernel(
    const void* __restrict__ ei, const int* __restrict__ flag,
    int* __restrict__ gcur, unsigned* __restrict__ pairs,
    const float* __restrict__ x, const float* __restrict__ W1,
    uint4* __restrict__ hs1u, int E, int nb, int pb, int N) {
    __shared__ alignas(16) char smem[47120];
    int tid = threadIdx.x;
    if ((int)blockIdx.x < pb) {
        int* cnt  = (int*)smem;                  // histogram, then per-bucket global base
        int* bbs  = (int*)(smem + 4096);         // local exclusive offsets (+ sentinel)
        int* cur  = (int*)(smem + 8208);         // scatter cursor
        int* ssum = (int*)(smem + 12304);        // scan scratch
        unsigned* stage = (unsigned*)(smem + 14352);
        const bool is64 = (*flag != 0);
        const long long* e64 = (const long long*)ei;
        const int* e32 = (const int*)ei;
        int e0 = blockIdx.x * P_EPB;
        int tot = E - e0; if (tot > P_EPB) tot = P_EPB;
        for (int b = tid; b < nb; b += PT) cnt[b] = 0;
        __syncthreads();
        // pass 1: read edges ONCE, histogram dst, keep packed value + bucket in registers
        unsigned pk[16];
        int bk[16];
#pragma unroll
        for (int k = 0; k < 16; ++k) {
            int i = tid + k * PT;
            bk[k] = -1;
            if (i < tot) {
                int e = e0 + i;
                int s, d;
                if (is64) { s = (int)e64[e]; d = (int)e64[E + e]; }
                else      { s = e32[e];      d = e32[E + e]; }
                int b = d >> BSHIFT;
                bk[k] = b;
                pk[k] = ((unsigned)s << BSHIFT) | (unsigned)(d & BMASK);
                atomicAdd(&cnt[b], 1);
            }
        }
        __syncthreads();
        // local scan (2 bins/thread) + global reservation
        int t2 = tid * 2;
        int c0 = (t2 < nb) ? cnt[t2] : 0;
        int c1 = (t2 + 1 < nb) ? cnt[t2 + 1] : 0;
        int ts = c0 + c1;
        ssum[tid] = ts;
        __syncthreads();
        for (int off = 1; off < PT; off <<= 1) {
            int v = (tid >= off) ? ssum[tid - off] : 0;
            __syncthreads();
            ssum[tid] += v;
            __syncthreads();
        }
        int excl = ssum[tid] - ts;
        if (tid == PT - 1) bbs[nb] = ssum[PT - 1];   // sentinel = staged total
        int gb0 = 0, gb1 = 0;
        if (t2 < nb && c0) gb0 = atomicAdd(&gcur[t2], c0);
        if (t2 + 1 < nb && c1) gb1 = atomicAdd(&gcur[t2 + 1], c1);
        if (t2 < nb)     { bbs[t2] = excl;          cnt[t2] = gb0;     cur[t2] = 0; }
        if (t2 + 1 < nb) { bbs[t2 + 1] = excl + c0; cnt[t2 + 1] = gb1; cur[t2 + 1] = 0; }
        __syncthreads();
        // pass 2: pure-LDS scatter into bucket-sorted stage
#pragma unroll
        for (int k = 0; k < 16; ++k) {
            if (bk[k] >= 0) {
                int r = atomicAdd(&cur[bk[k]], 1);
                stage[bbs[bk[k]] + r] = pk[k];
            }
        }
        __syncthreads();
        // pass 3: coalesced write of per-bucket runs (binary search for bucket)
        for (int i = tid; i < tot; i += PT) {
            int lo = 0, hi = nb;
            while (hi - lo > 1) { int mid = (lo + hi) >> 1; if (bbs[mid] <= i) lo = mid; else hi = mid; }
            int slot = cnt[lo] + (i - bbs[lo]);
            if (slot < CAP) pairs[(size_t)lo * CAP + slot] = stage[i];
        }
    } else {
        // ---- layer-1 GEMM: hs1u = bf16(x @ W1), unscaled ----
        float* Ws = (float*)smem;
        for (int i = tid; i < 2048; i += PT) Ws[i] = W1[i];
        __syncthreads();
        int n = ((int)blockIdx.x - pb) * PT + tid;
        if (n >= N) return;
        const float4* xp = (const float4*)(x + (size_t)n * 128);
        float a[16];
#pragma unroll
        for (int j = 0; j < 16; ++j) a[j] = 0.f;
#pragma unroll 4
        for (int k4 = 0; k4 < 32; ++k4) {
            float4 xv = xp[k4];
            const float* wr = &Ws[k4 * 64];
#pragma unroll
            for (int j = 0; j < 16; ++j) a[j] += xv.x * wr[j];
#pragma unroll
            for (int j = 0; j < 16; ++j) a[j] += xv.y * wr[16 + j];
#pragma unroll
            for (int j = 0; j < 16; ++j) a[j] += xv.z * wr[32 + j];
#pragma unroll
            for (int j = 0; j < 16; ++j) a[j] += xv.w * wr[48 + j];
        }
        uint4 u0, u1;
        u0.x = pkbf2(a[0], a[1]);   u0.y = pkbf2(a[2], a[3]);
        u0.z = pkbf2(a[4], a[5]);   u0.w = pkbf2(a[6], a[7]);
        u1.x = pkbf2(a[8], a[9]);   u1.y = pkbf2(a[10], a[11]);
        u1.z = pkbf2(a[12], a[13]); u1.w = pkbf2(a[14], a[15]);
        hs1u[(size_t)n * 2]     = u0;
        hs1u[(size_t)n * 2 + 1] = u1;
    }
}

// ---------------- counting sort -> fixed-slice CSR + deg + scaled bf16 pack of hs1 ----------------
__global__ __launch_bounds__(TPB) void csr_build_kernel(
    const unsigned* __restrict__ pairs, const int* __restrict__ gcur,
    int* __restrict__ csr, int* __restrict__ row, int* __restrict__ degA,
    const uint4* __restrict__ hs1u, uint4* __restrict__ hs1b, int N) {
    __shared__ int hist[BNODES];
    __shared__ int sc[BNODES];
    __shared__ int cur[BNODES];
    __shared__ int stage[CAP];
    int tid = threadIdx.x;
    int b = blockIdx.x;
    if (tid < BNODES) hist[tid] = 0;
    __syncthreads();
    int cnt = gcur[b]; if (cnt > CAP) cnt = CAP;
    int base = b * CAP;  // fixed slice: no global scan needed
    const unsigned* sl = pairs + (size_t)b * CAP;
    for (int i = tid; i < cnt; i += TPB)
        atomicAdd(&hist[sl[i] & BMASK], 1);
    __syncthreads();
    if (tid < BNODES) sc[tid] = hist[tid];
    __syncthreads();
    for (int off = 1; off < BNODES; off <<= 1) {
        int u = (tid < BNODES && tid >= off) ? sc[tid - off] : 0;
        __syncthreads();
        if (tid < BNODES) sc[tid] += u;
        __syncthreads();
    }
    if (tid < BNODES) {
        int excl = sc[tid] - hist[tid];
        sc[tid] = excl;
        cur[tid] = 0;
        int node = (b << BSHIFT) + tid;
        if (node < N) {
            row[node]  = base + excl;
            degA[node] = hist[tid];
        }
    }
    __syncthreads();
    for (int i = tid; i < cnt; i += TPB) {
        unsigned val = sl[i];
        int l = val & BMASK;
        int r = atomicAdd(&cur[l], 1);
        stage[sc[l] + r] = (int)(val >> BSHIFT);
    }
    __syncthreads();
    for (int i = tid; i < cnt; i += TPB)
        csr[base + i] = stage[i];
    // scale by dinv + repack: hs1b[node] = bf16(dinv * hs1u[node])
    {
        int ln = tid >> 1, half = tid & 1;
        int node = (b << BSHIFT) + ln;
        if (node < N) {
            float s = rsqrtf((float)(hist[ln] + 1));   // +1 self-loop
            uint4 uu = hs1u[(size_t)node * 2 + half];
            uint4 o;
            o.x = pkbf2(bflo(uu.x) * s, bfhi(uu.x) * s);
            o.y = pkbf2(bflo(uu.y) * s, bfhi(uu.y) * s);
            o.z = pkbf2(bflo(uu.z) * s, bfhi(uu.z) * s);
            o.w = pkbf2(bflo(uu.w) * s, bfhi(uu.w) * s);
            hs1b[(size_t)node * 2 + half] = o;
        }
    }
}

// ---------------- agg1: per-node bf16 register gather (8 lanes/node) + fused layer2 ----------------
__global__ __launch_bounds__(TPB) void agg1_kernel(
    const uint4* __restrict__ hs1b, const int* __restrict__ csr,
    const int* __restrict__ row, const int* __restrict__ degA,
    const float* __restrict__ W2, const float* __restrict__ b1,
    uint4* __restrict__ hs2b, int N) {
    __shared__ float Ws[112];
    __shared__ float bs[16];
    int tid = threadIdx.x;
    if (tid < 112) Ws[tid] = W2[tid];
    if (tid < 16) bs[tid] = b1[tid];
    __syncthreads();
    int g = blockIdx.x * TPB + tid;
    int n = g >> 3, oct = g & 7;
    int st = 0, cnt = 0;
    if (n < N) { st = row[n]; cnt = degA[n]; }
    float acc[16];
#pragma unroll
    for (int j = 0; j < 16; ++j) acc[j] = 0.f;
    int i = st + oct, end = st + cnt;
    for (; i + 8 < end; i += 16) {
        int s0 = csr[i], s1 = csr[i + 8];
        uint4 g0 = hs1b[(size_t)s0 * 2], g1 = hs1b[(size_t)s0 * 2 + 1];
        uint4 h0 = hs1b[(size_t)s1 * 2], h1 = hs1b[(size_t)s1 * 2 + 1];
        acc[0]  += bflo(g0.x) + bflo(h0.x); acc[1]  += bfhi(g0.x) + bfhi(h0.x);
        acc[2]  += bflo(g0.y) + bflo(h0.y); acc[3]  += bfhi(g0.y) + bfhi(h0.y);
        acc[4]  += bflo(g0.z) + bflo(h0.z); acc[5]  += bfhi(g0.z) + bfhi(h0.z);
        acc[6]  += bflo(g0.w) + bflo(h0.w); acc[7]  += bfhi(g0.w) + bfhi(h0.w);
        acc[8]  += bflo(g1.x) + bflo(h1.x); acc[9]  += bfhi(g1.x) + bfhi(h1.x);
        acc[10] += bflo(g1.y) + bflo(h1.y); acc[11] += bfhi(g1.y) + bfhi(h1.y);
        acc[12] += bflo(g1.z) + bflo(h1.z); acc[13] += bfhi(g1.z) + bfhi(h1.z);
        acc[14] += bflo(g1.w) + bflo(h1.w); acc[15] += bfhi(g1.w) + bfhi(h1.w);
    }
    if (i < end) {
        int s0 = csr[i];
        uint4 g0 = hs1b[(size_t)s0 * 2], g1 = hs1b[(size_t)s0 * 2 + 1];
        acc[0]  += bflo(g0.x); acc[1]  += bfhi(g0.x);
        acc[2]  += bflo(g0.y); acc[3]  += bfhi(g0.y);
        acc[4]  += bflo(g0.z); acc[5]  += bfhi(g0.z);
        acc[6]  += bflo(g0.w); acc[7]  += bfhi(g0.w);
        acc[8]  += bflo(g1.x); acc[9]  += bfhi(g1.x);
        acc[10] += bflo(g1.y); acc[11] += bfhi(g1.y);
        acc[12] += bflo(g1.z); acc[13] += bfhi(g1.z);
        acc[14] += bflo(g1.w); acc[15] += bfhi(g1.w);
    }
#pragma unroll
    for (int j = 0; j < 16; ++j) {
        acc[j] += __shfl_xor(acc[j], 1);
        acc[j] += __shfl_xor(acc[j], 2);
        acc[j] += __shfl_xor(acc[j], 4);
    }
    if (oct == 0 && n < N) {
        float sc = rsqrtf((float)(cnt + 1));
        uint4 sA = hs1b[(size_t)n * 2], sB = hs1b[(size_t)n * 2 + 1];
        float self[16] = {bflo(sA.x), bfhi(sA.x), bflo(sA.y), bfhi(sA.y),
                          bflo(sA.z), bfhi(sA.z), bflo(sA.w), bfhi(sA.w),
                          bflo(sB.x), bfhi(sB.x), bflo(sB.y), bfhi(sB.y),
                          bflo(sB.z), bfhi(sB.z), bflo(sB.w), bfhi(sB.w)};
        float v[16];
#pragma unroll
        for (int j = 0; j < 16; ++j)
            v[j] = fmaxf(0.f, sc * (acc[j] + self[j]) + bs[j]);
        float h[7];
#pragma unroll
        for (int j = 0; j < 7; ++j) h[j] = 0.f;
#pragma unroll
        for (int k = 0; k < 16; ++k)
#pragma unroll
            for (int j = 0; j < 7; ++j) h[j] += v[k] * Ws[k * 7 + j];
        uint4 u;
        u.x = pkbf2(h[0] * sc, h[1] * sc);
        u.y = pkbf2(h[2] * sc, h[3] * sc);
        u.z = pkbf2(h[4] * sc, h[5] * sc);
        u.w = pkbf2(h[6] * sc, 0.f);
        hs2b[n] = u;
    }
}

// ---------------- agg2: per-node bf16 gather (8 lanes/node, 1 uint4/edge) + bias/log-softmax ----------------
__global__ __launch_bounds__(TPB) void agg2_kernel(
    const uint4* __restrict__ hs2b, const int* __restrict__ csr,
    const int* __restrict__ row, const int* __restrict__ degA,
    const float* __restrict__ b2, float* __restrict__ out, int N) {
    __shared__ float bs[8];
    if (threadIdx.x < 7) bs[threadIdx.x] = b2[threadIdx.x];
    __syncthreads();
    int g = blockIdx.x * TPB + threadIdx.x;
    int n = g >> 3, oct = g & 7;
    int st = 0, cnt = 0;
    if (n < N) { st = row[n]; cnt = degA[n]; }
    float acc[7];
#pragma unroll
    for (int j = 0; j < 7; ++j) acc[j] = 0.f;
    int i = st + oct, end = st + cnt;
    for (; i + 8 < end; i += 16) {
        int s0 = csr[i], s1 = csr[i + 8];
        uint4 q = hs2b[s0];
        uint4 r = hs2b[s1];
        acc[0] += bflo(q.x) + bflo(r.x); acc[1] += bfhi(q.x) + bfhi(r.x);
        acc[2] += bflo(q.y) + bflo(r.y); acc[3] += bfhi(q.y) + bfhi(r.y);
        acc[4] += bflo(q.z) + bflo(r.z); acc[5] += bfhi(q.z) + bfhi(r.z);
        acc[6] += bflo(q.w) + bflo(r.w);
    }
    if (i < end) {
        uint4 q = hs2b[csr[i]];
        acc[0] += bflo(q.x); acc[1] += bfhi(q.x);
        acc[2] += bflo(q.y); acc[3] += bfhi(q.y);
        acc[4] += bflo(q.z); acc[5] += bfhi(q.z);
        acc[6] += bflo(q.w);
    }
#pragma unroll
    for (int j = 0; j < 7; ++j) {
        acc[j] += __shfl_xor(acc[j], 1);
        acc[j] += __shfl_xor(acc[j], 2);
        acc[j] += __shfl_xor(acc[j], 4);
    }
    if (oct == 0 && n < N) {
        float sc = rsqrtf((float)(cnt + 1));
        uint4 q = hs2b[n];
        float self[7] = {bflo(q.x), bfhi(q.x), bflo(q.y), bfhi(q.y),
                         bflo(q.z), bfhi(q.z), bflo(q.w)};
        float v[7];
#pragma unroll
        for (int j = 0; j < 7; ++j)
            v[j] = sc * (acc[j] + self[j]) + bs[j];
        float m = v[0];
#pragma unroll
        for (int j = 1; j < 7; ++j) m = fmaxf(m, v[j]);
        float ssum = 0.f;
#pragma unroll
        for (int j = 0; j < 7; ++j) ssum += __expf(v[j] - m);
        float l = m + __logf(ssum);
        float* op = out + (size_t)n * 7;
#pragma unroll
        for (int j = 0; j < 7; ++j) op[j] = v[j] - l;
    }
}

extern "C" void kernel_launch(void* const* d_in, const int* in_sizes, int n_in,
                              void* d_out, int out_size, void* d_ws, size_t ws_size,
                              hipStream_t stream) {
    const float* x  = (const float*)d_in[0];
    const void*  ei = d_in[1];
    const float* W1 = (const float*)d_in[2];
    const float* b1 = (const float*)d_in[3];
    const float* W2 = (const float*)d_in[4];
    const float* b2 = (const float*)d_in[5];
    float* out = (float*)d_out;

    const int Hh  = in_sizes[3];            // 16
    const int Fin = in_sizes[2] / Hh;       // 128
    const int N   = in_sizes[0] / Fin;      // 100000
    const long long twoE = in_sizes[1];
    const int E = (int)(twoE / 2);          // 3200000
    const int nb = (N + BNODES - 1) >> BSHIFT;  // 782 buckets of 128 nodes
    (void)n_in; (void)out_size; (void)ws_size;

    char* p = (char*)d_ws;
    auto alloc = [&](size_t bytes) {
        char* r = p;
        p += (bytes + 63) & ~(size_t)63;
        return r;
    };
    int*      flag  = (int*)alloc(sizeof(int));
    int*      gcur  = (int*)alloc(sizeof(int) * (size_t)nb);
    unsigned* pairs = (unsigned*)alloc(sizeof(unsigned) * (size_t)nb * CAP);  // 19.2 MB
    int*      csr   = (int*)alloc(sizeof(int) * (size_t)nb * CAP);            // 19.2 MB (fixed slices)
    int*      rowA  = (int*)alloc(sizeof(int) * (size_t)N);
    int*      degA  = (int*)alloc(sizeof(int) * (size_t)N);
    uint4*    hs1u  = (uint4*)alloc(32 * (size_t)N);                          // 3.2 MB bf16 unscaled
    uint4*    hs1b  = (uint4*)alloc(32 * (size_t)N);                          // 3.2 MB bf16 scaled
    uint4*    hs2b  = (uint4*)alloc(16 * (size_t)N);                          // 1.6 MB bf16

    const int pb = (E + P_EPB - 1) / P_EPB;   // 391 place blocks
    const int gb = (N + PT - 1) / PT;         // 196 gemm blocks

    detect_kernel<<<1, 256, 0, stream>>>((const unsigned int*)ei, flag, gcur, nb);
    fused_place_gemm_kernel<<<pb + gb, PT, 0, stream>>>(
        ei, flag, gcur, pairs, x, W1, hs1u, E, nb, pb, N);
    csr_build_kernel<<<nb, TPB, 0, stream>>>(pairs, gcur, csr, rowA, degA, hs1u, hs1b, N);
    agg1_kernel<<<(8 * N + TPB - 1) / TPB, TPB, 0, stream>>>(hs1b, csr, rowA, degA, W2, b1, hs2b, N);
    agg2_kernel<<<(8 * N + TPB - 1) / TPB, TPB, 0, stream>>>(hs2b, csr, rowA, degA, b2, out, N);
}